// Round 20
// baseline (333.565 us; speedup 1.0000x reference)
//
#include <hip/hip_runtime.h>
#include <math.h>

#define BATCH 131072
#define NTOT 320

typedef __attribute__((ext_vector_type(8))) short short8;
typedef __attribute__((ext_vector_type(4))) float f32x4;

// ---- ws layout (float offsets) ----
#define WS_D22   0          // 32*64
#define WS_VR    2048       // 320*64
#define WS_T     22528      // 320*64
#define WS_H     43008      // 320*320
#define WS_E     145408     // 128*128
#define WS_EINV  161792     // 128*128
#define WS_WEXT  178176     // 128*256
#define WS_D11   210944     // 64*64
#define WS_ILAM  215040     // 64
#define WS_BFU   215104     // ushort region below
#define U_WATH 0
#define U_WATL 16384
#define U_WOT  32768
#define U_WSPH 40960
#define U_WSPL 73728
// transient scratch inside WS_H:
#define WS_RC   (WS_H + 2048)   // 64*64  R_cal -> Rinv (in place)
#define SC_AI   (WS_H)          // 64*64
#define SC_P    (WS_H + 4096)
#define SC_S    (WS_H + 8192)
#define SC_Q    (WS_H + 12288)
#define SC_R    (WS_H + 16384)

__device__ inline unsigned short f2bf(float x){
    unsigned u = __builtin_bit_cast(unsigned, x);
    u += 0x7FFFu + ((u >> 16) & 1u);
    return (unsigned short)(u >> 16);
}
__device__ inline float bf2f(unsigned short h){
    unsigned u = ((unsigned)h) << 16;
    return __builtin_bit_cast(float, u);
}
__device__ inline float r_diag(int j) {
    return (j < 16 || j == 39) ? 100000.0f : 0.001f;
}

// ---------------------------------------------------------------------------
// kF_abc: fused M -> GJ32 -> D22 -> R_cal.  1 block, 1024 threads.
// All proven forms, LDS-resident (no M/Minv ws round-trips).
// ---------------------------------------------------------------------------
__global__ __launch_bounds__(1024) void kF_abc(
    const float* __restrict__ X3, const float* __restrict__ Y3,
    const float* __restrict__ Z3, float* __restrict__ ws)
{
    __shared__ float Msh[32*33];
    __shared__ float A32[32*33];
    __shared__ float D22s[2048];
    const int t = threadIdx.x;
    const int i = t >> 5, j = t & 31;
    {
        float s = 0.f;
        for (int k = 0; k < 32; ++k)
            s += X3[k*32+i]*X3[k*32+j] + Z3[k*32+i]*Z3[k*32+j];
        s += Y3[i*32+j] - Y3[j*32+i];
        if (i == j) s += 0.001f;
        Msh[i*33+j] = s;
        A32[i*33+j] = s + (i == j ? 1.f : 0.f);
    }
    __syncthreads();
    for (int k = 0; k < 32; ++k) {
        float ip = 1.f / A32[k*33+k];
        float f  = A32[i*33+k];
        float pj = A32[k*33+j];
        __syncthreads();
        float nv;
        if (i == k) nv = (j == k) ? ip : pj*ip;
        else        nv = (j == k) ? (-f*ip) : (A32[i*33+j] - f*ip*pj);
        A32[i*33+j] = nv;
        __syncthreads();
    }
    for (int idx = t; idx < 2048; idx += 1024) {
        int i2 = idx >> 6, j2 = idx & 63;
        float s = 0.f;
        if (j2 < 32) {
            for (int k = 0; k < 32; ++k) {
                float im = (k == j2 ? 1.f : 0.f) - Msh[k*33+j2];
                s += A32[i2*33+k]*im;
            }
        } else {
            int jj = j2 - 32;
            for (int k = 0; k < 32; ++k) s += A32[i2*33+k]*Z3[jj*32+k];
            s *= -2.f;
        }
        float d22 = s * sqrtf(r_diag(j2)) * 0.31622776601683794f;
        D22s[idx] = d22;
        ws[WS_D22 + idx] = d22;
    }
    __syncthreads();
    for (int idx = t; idx < 4096; idx += 1024) {
        int i2 = idx >> 6, j2 = idx & 63;
        float s = 0.f;
        for (int k = 0; k < 32; ++k) s += D22s[k*64+i2]*D22s[k*64+j2];
        float v = -10.f*s;
        if (i2 == j2) v += r_diag(i2);
        ws[WS_RC + idx] = v;
    }
}

// ---------------------------------------------------------------------------
// GJ64 generic: 256 threads, q-uniform, Ar[16] register (PROVEN shape).
// ---------------------------------------------------------------------------
__global__ __launch_bounds__(256) void kS_gj64g(float* __restrict__ ws,
    int srcOff, int srcStride, int dstOff, int dstStride)
{
    __shared__ float piv[2][64];
    __shared__ float fcol[2][64];
    __shared__ float ipd[2];
    const int t = threadIdx.x;
    const int q = t >> 6;
    const int i = t & 63;
    const int c0 = q*16;

    float Ar[16];
    {
        const float* Rin = ws + srcOff + i*srcStride + c0;
        #pragma unroll
        for (int jj = 0; jj < 4; ++jj) {
            float4 v = *(const float4*)(Rin + jj*4);
            Ar[jj*4+0]=v.x; Ar[jj*4+1]=v.y; Ar[jj*4+2]=v.z; Ar[jj*4+3]=v.w;
        }
    }
    for (int k = 0; k < 64; ++k) {
        const int b  = k & 1;
        const int kq = k >> 4;
        const int kj = k & 15;
        float f_own = Ar[0];
        #pragma unroll
        for (int jj = 1; jj < 16; ++jj) f_own = (jj == kj) ? Ar[jj] : f_own;
        if (q == kq) fcol[b][i] = f_own;
        if (i == k) {
            #pragma unroll
            for (int jj = 0; jj < 4; ++jj) {
                float4 v;
                v.x = Ar[jj*4+0] + ((q==kq && jj*4+0==kj) ? 1.f : 0.f);
                v.y = Ar[jj*4+1] + ((q==kq && jj*4+1==kj) ? 1.f : 0.f);
                v.z = Ar[jj*4+2] + ((q==kq && jj*4+2==kj) ? 1.f : 0.f);
                v.w = Ar[jj*4+3] + ((q==kq && jj*4+3==kj) ? 1.f : 0.f);
                *(float4*)(&piv[b][c0 + jj*4]) = v;
            }
            if (q == kq) ipd[b] = 1.f / f_own;
        }
        __syncthreads();
        const float ipv = ipd[b];
        if (i == k) {
            #pragma unroll
            for (int jj = 0; jj < 16; ++jj)
                Ar[jj] = (q==kq && jj==kj) ? ipv : Ar[jj]*ipv;
        } else {
            const float g = fcol[b][i] * ipv;
            #pragma unroll
            for (int jj = 0; jj < 4; ++jj) {
                float4 pv = *(const float4*)(&piv[b][c0 + jj*4]);
                Ar[jj*4+0] -= g*pv.x;
                Ar[jj*4+1] -= g*pv.y;
                Ar[jj*4+2] -= g*pv.z;
                Ar[jj*4+3] -= g*pv.w;
            }
        }
    }
    {
        float* Rout = ws + dstOff + i*dstStride + c0;
        #pragma unroll
        for (int jj = 0; jj < 4; ++jj) {
            float4 v;
            v.x=Ar[jj*4+0]; v.y=Ar[jj*4+1]; v.z=Ar[jj*4+2]; v.w=Ar[jj*4+3];
            *(float4*)(Rout + jj*4) = v;
        }
    }
}

// ---------------------------------------------------------------------------
// vec_r, T (80 blocks each; proven)
// ---------------------------------------------------------------------------
__global__ __launch_bounds__(256) void k_vecr(
    const float* __restrict__ B2, const float* __restrict__ C2,
    const float* __restrict__ D21, const float* __restrict__ D12,
    float* __restrict__ ws)
{
    int idx = blockIdx.x*256 + threadIdx.x;
    if (idx >= 320*64) return;
    int i = idx >> 6, j = idx & 63;
    const float* D22 = ws + WS_D22;
    float v;
    if (i < 128) {
        float s = 0.f;
        for (int k = 0; k < 32; ++k) s += C2[k*128+i]*D22[k*64+j];
        v = -10.f*s;
    } else if (i < 192) {
        int ii = i - 128;
        float s = 0.f;
        for (int k = 0; k < 32; ++k) s += D21[k*64+ii]*D22[k*64+j];
        v = -10.f*s - D12[ii*64+j];
    } else {
        v = B2[(i-192)*64 + j];
    }
    ws[WS_VR+idx] = v;
}

__global__ __launch_bounds__(256) void k_T(float* __restrict__ ws)
{
    int idx = blockIdx.x*256 + threadIdx.x;
    if (idx >= 320*64) return;
    int i = idx >> 6, j = idx & 63;
    const float* VR = ws + WS_VR + i*64;
    const float* RC = ws + WS_RC;
    float s = 0.f;
    for (int k = 0; k < 64; ++k) s += VR[k] * RC[k*64+j];
    ws[WS_T+idx] = s;
}

// ---------------------------------------------------------------------------
// K2: H
// ---------------------------------------------------------------------------
__global__ void k_H(const float* __restrict__ X, const float* __restrict__ C2,
                    const float* __restrict__ D21, float* __restrict__ ws)
{
    int idx = blockIdx.x*256 + threadIdx.x;
    if (idx >= NTOT*NTOT) return;
    int i = idx / NTOT, j = idx % NTOT;
    float s = (i == j) ? 0.001f : 0.f;
    for (int k = 0; k < NTOT; ++k) s += X[k*NTOT+i]*X[k*NTOT+j];
    const float* T  = ws + WS_T;
    const float* vr = ws + WS_VR;
    float s2 = 0.f;
    for (int k = 0; k < 64; ++k) s2 += T[i*64+k]*vr[j*64+k];
    s += s2;
    if (i < 192 && j < 192) {
        float s3 = 0.f;
        for (int k = 0; k < 32; ++k) {
            float qi = (i < 128) ? C2[k*128+i] : D21[k*64 + (i-128)];
            float qj = (j < 128) ? C2[k*128+j] : D21[k*64 + (j-128)];
            s3 += qi*qj;
        }
        s += 10.f*s3;
    }
    ws[WS_H + idx] = s;
}

// ---------------------------------------------------------------------------
// K3: extract
// ---------------------------------------------------------------------------
__global__ void k_extract(const float* __restrict__ Y1, const float* __restrict__ C2,
                          const float* __restrict__ D21, const float* __restrict__ D12,
                          const float* __restrict__ B2, float* __restrict__ ws)
{
    const float* H = ws + WS_H;
    unsigned short* bfb = (unsigned short*)(ws + WS_BFU);
    int tid = blockIdx.x*blockDim.x + threadIdx.x;
    int nth = gridDim.x*blockDim.x;
    for (int idx = tid; idx < 128*128; idx += nth) {
        int i = idx >> 7, j = idx & 127;
        ws[WS_E+idx] = 0.5f*(H[i*320+j] + H[(192+i)*320 + 192+j] + Y1[i*128+j] - Y1[j*128+i]);
    }
    for (int i = tid; i < 64; i += nth)
        ws[WS_ILAM+i] = 2.0f / H[(128+i)*320 + 128+i];
    for (int idx = tid; idx < 64*64; idx += nth) {
        int i = idx >> 6, j = idx & 63;
        ws[WS_D11+idx] = (j < i) ? -H[(128+i)*320 + 128+j] : 0.f;
    }
    for (int idx = tid; idx < 128*256; idx += nth) {
        int m = idx >> 8, k = idx & 255;
        ws[WS_WEXT+idx] = (k < 192) ? H[(192+m)*320 + k] : B2[m*64 + (k-192)];
    }
    for (int idx = tid; idx < 64*256; idx += nth) {
        int j = idx >> 8, k = idx & 255;
        float v;
        if (k < 128)      v = -H[(128+j)*320 + k];
        else if (k < 192) v = 0.f;
        else              v = D12[j*64 + (k-192)];
        unsigned short hi = f2bf(v);
        bfb[U_WATH+idx] = hi;
        bfb[U_WATL+idx] = f2bf(v - bf2f(hi));
    }
    const float* D22 = ws + WS_D22;
    for (int idx = tid; idx < 32*256; idx += nth) {
        int c = idx >> 8, k = idx & 255;
        float v;
        if (k < 128)      v = C2[c*128+k];
        else if (k < 192) v = D21[c*64 + (k-128)];
        else              v = D22[c*64 + (k-192)];
        bfb[U_WOT+idx] = f2bf(v);
    }
}

// ---------------------------------------------------------------------------
// Schur GEMM pieces. kS_PQ merges P and Q (both depend only on Ai).
// ---------------------------------------------------------------------------
__global__ __launch_bounds__(256) void kS_PQ(float* __restrict__ ws)
{
    int gid = blockIdx.x*256 + threadIdx.x;
    const float* E  = ws + WS_E;
    if (gid < 4096) {                 // P = Ai @ B
        int i = gid >> 6, j = gid & 63;
        const float* AI = ws + SC_AI + i*64;
        float s = 0.f;
        for (int k = 0; k < 64; ++k) s += AI[k] * E[k*128 + 64 + j];
        ws[SC_P + gid] = s;
    } else {                          // Q = C @ Ai
        int idx = gid - 4096;
        int i = idx >> 6, j = idx & 63;
        const float* C = E + (64+i)*128;
        const float* AI = ws + SC_AI;
        float s = 0.f;
        for (int k = 0; k < 64; ++k) s += C[k] * AI[k*64 + j];
        ws[SC_Q + idx] = s;
    }
}
__global__ __launch_bounds__(256) void kS_S(float* __restrict__ ws)
{
    int idx = blockIdx.x*256 + threadIdx.x;
    int i = idx >> 6, j = idx & 63;
    const float* E = ws + WS_E;
    const float* C = E + (64+i)*128;
    const float* P = ws + SC_P;
    float s = E[(64+i)*128 + 64 + j];
    for (int k = 0; k < 64; ++k) s -= C[k] * P[k*64 + j];
    ws[SC_S + idx] = s;
}
__global__ __launch_bounds__(256) void kS_R(float* __restrict__ ws)
{
    int idx = blockIdx.x*256 + threadIdx.x;
    int i = idx >> 6, j = idx & 63;
    const float* Si = ws + SC_S + i*64;
    const float* Q  = ws + SC_Q;
    float s = 0.f;
    for (int k = 0; k < 64; ++k) s += Si[k] * Q[k*64 + j];
    ws[SC_R + idx] = s;
    ws[WS_EINV + (64+i)*128 + j] = -s;
}
__global__ __launch_bounds__(256) void kS_TL(float* __restrict__ ws)
{
    int idx = blockIdx.x*256 + threadIdx.x;
    int i = idx >> 6, j = idx & 63;
    const float* P  = ws + SC_P + i*64;
    const float* R2 = ws + SC_R;
    const float* Si = ws + SC_S;
    float s1 = ws[SC_AI + idx];
    float s2 = 0.f;
    for (int k = 0; k < 64; ++k) {
        s1 += P[k] * R2[k*64 + j];
        s2 += P[k] * Si[k*64 + j];
    }
    ws[WS_EINV + i*128 + j]           = s1;
    ws[WS_EINV + i*128 + 64 + j]      = -s2;
    ws[WS_EINV + (64+i)*128 + 64 + j] = Si[i*64 + j];
}

// ---------------------------------------------------------------------------
// K5: Wsp
// ---------------------------------------------------------------------------
__global__ __launch_bounds__(256) void k_Wsp(float* __restrict__ ws)
{
    int i = blockIdx.x;
    int k = threadIdx.x;
    const float* Einv = ws + WS_EINV + i*128;
    const float* WexT = ws + WS_WEXT;
    unsigned short* bfb = (unsigned short*)(ws + WS_BFU);
    float s = 0.f;
    for (int m = 0; m < 128; ++m) s += Einv[m] * WexT[m*256 + k];
    unsigned short hi = f2bf(s);
    bfb[U_WSPH + i*256 + k] = hi;
    bfb[U_WSPL + i*256 + k] = f2bf(s - bf2f(hi));
}

// ---------------------------------------------------------------------------
// K6: batch kernel, ROWS=32 (LDS 24.25KB -> 6 blocks/CU; R6->R7 occupancy
// lever). 8 lanes/row in recurrence (8 acc each, chunk-aligned a/w IO).
// ---------------------------------------------------------------------------
#define ROWS 32
__global__ __launch_bounds__(256, 6) void k_batch(
    const float* __restrict__ inpt, const float* __restrict__ state,
    const float* __restrict__ ws, float* __restrict__ out)
{
    __shared__ unsigned short zsh[ROWS*256];   // 16384 B
    __shared__ unsigned short D11t[64*64];     // 8192 B (transposed, bf16, iL diag)
    const int t = threadIdx.x;
    const int row0 = blockIdx.x * ROWS;
    const unsigned short* bfb = (const unsigned short*)(ws + WS_BFU);

    for (int idx = t; idx < ROWS*16; idx += 256) {
        int r = idx >> 4, c = idx & 15;
        const float4* p = (const float4*)(state + (size_t)(row0+r)*128 + c*8);
        float4 f0 = p[0], f1 = p[1];
        short8 h;
        h[0]=(short)f2bf(f0.x); h[1]=(short)f2bf(f0.y); h[2]=(short)f2bf(f0.z); h[3]=(short)f2bf(f0.w);
        h[4]=(short)f2bf(f1.x); h[5]=(short)f2bf(f1.y); h[6]=(short)f2bf(f1.z); h[7]=(short)f2bf(f1.w);
        *(short8*)(&zsh[r*256 + ((c ^ (r&7)) << 3)]) = h;
    }
    for (int idx = t; idx < ROWS*8; idx += 256) {
        int r = idx >> 3, cl = idx & 7, c = 24 + cl;
        const float4* p = (const float4*)(inpt + (size_t)(row0+r)*64 + cl*8);
        float4 f0 = p[0], f1 = p[1];
        short8 h;
        h[0]=(short)f2bf(f0.x); h[1]=(short)f2bf(f0.y); h[2]=(short)f2bf(f0.z); h[3]=(short)f2bf(f0.w);
        h[4]=(short)f2bf(f1.x); h[5]=(short)f2bf(f1.y); h[6]=(short)f2bf(f1.z); h[7]=(short)f2bf(f1.w);
        *(short8*)(&zsh[r*256 + ((c ^ (r&7)) << 3)]) = h;
    }
    for (int idx = t; idx < 4096; idx += 256) {
        int j = idx >> 6, i = idx & 63;
        float v = (i == j) ? ws[WS_ILAM + j] : ws[WS_D11 + i*64 + j];
        D11t[idx] = f2bf(v);
    }
    __syncthreads();

    const int wv = t >> 6, lane = t & 63, lr = lane & 15, lk = lane >> 4;

    // ---- phase 1: a = z @ Wa (hi+lo) ----
    {
        const unsigned short* WATH = bfb + U_WATH;
        const unsigned short* WATL = bfb + U_WATL;
        f32x4 acc1[2] = {};
        const int ks1[6] = {0,1,2,3,6,7};
        #pragma unroll
        for (int s = 0; s < 6; ++s) {
            int ks = ks1[s];
            short8 bh = *(const short8*)(&WATH[(wv*16+lr)*256 + ks*32 + lk*8]);
            short8 bl = *(const short8*)(&WATL[(wv*16+lr)*256 + ks*32 + lk*8]);
            #pragma unroll
            for (int rt = 0; rt < 2; ++rt) {
                int row = rt*16 + lr, c = ks*4 + lk;
                short8 a = *(const short8*)(&zsh[row*256 + ((c ^ (row&7)) << 3)]);
                acc1[rt] = __builtin_amdgcn_mfma_f32_16x16x32_bf16(a, bh, acc1[rt], 0, 0, 0);
                acc1[rt] = __builtin_amdgcn_mfma_f32_16x16x32_bf16(a, bl, acc1[rt], 0, 0, 0);
            }
        }
        __syncthreads();
        const int ac = wv*16 + lr;
        const int cch = 16 + (ac >> 3), coff = ac & 7;
        #pragma unroll
        for (int rt = 0; rt < 2; ++rt)
            #pragma unroll
            for (int r = 0; r < 4; ++r) {
                int row = rt*16 + lk*4 + r;
                zsh[row*256 + ((cch ^ (row&7)) << 3) + coff] = f2bf(acc1[rt][r]);
            }
    }
    __syncthreads();

    // ---- recurrence: 8 lanes/row, lane owns i = qq*8..qq*8+7 ----
    {
        const int r  = wv*8 + (lane >> 3);    // 4 waves x 8 = 32 rows
        const int qq = lane & 7;
        float acc[8];
        {   // a-init: exactly chunk 16+qq of row r
            short8 av = *(const short8*)(&zsh[r*256 + (((16+qq) ^ (r&7)) << 3)]);
            #pragma unroll
            for (int s = 0; s < 8; ++s) acc[s] = bf2f((unsigned short)av[s]);
        }
        float wloc[8];
        #pragma unroll
        for (int j = 0; j < 64; ++j) {
            float diag = bf2f(D11t[j*64 + j]);    // iL[j], uniform
            float v = acc[j & 7];
            float x = v * diag;
            float e = __expf(2.f*x);
            float wc = 1.f - __fdividef(2.f, e + 1.f);
            int src = (lane & 0x38) | (j >> 3);
            float wj = __shfl(wc, src, 64);
            if ((j >> 3) == qq) wloc[j & 7] = wj;  // static (j unrolled)
            #pragma unroll
            for (int s = 0; s < 8; ++s)
                acc[s] += wj * bf2f(D11t[j*64 + qq*8 + s]);   // 8 banks, bcast
        }
        {   // w-write: one short8 at chunk 16+qq
            short8 h;
            #pragma unroll
            for (int e2 = 0; e2 < 8; ++e2) h[e2] = (short)f2bf(wloc[e2]);
            *(short8*)(&zsh[r*256 + (((16+qq) ^ (r&7)) << 3)]) = h;
        }
    }
    __syncthreads();

    // ---- phase 3: [out | state_plus] ----
    {
        const unsigned short* WOT  = bfb + U_WOT;
        const unsigned short* WSPH = bfb + U_WSPH;
        const unsigned short* WSPL = bfb + U_WSPL;
        f32x4 acc[3][2] = {};
        const int nt = (wv < 2) ? 3 : 2;
        #pragma unroll
        for (int ks = 0; ks < 8; ++ks) {
            short8 afr[2];
            #pragma unroll
            for (int rt = 0; rt < 2; ++rt) {
                int row = rt*16 + lr, c = ks*4 + lk;
                afr[rt] = *(const short8*)(&zsh[row*256 + ((c ^ (row&7)) << 3)]);
            }
            #pragma unroll
            for (int tt = 0; tt < 3; ++tt) {
                if (tt < nt) {
                    int ct = wv + tt*4;
                    if (ct < 2) {
                        short8 b = *(const short8*)(&WOT[(ct*16+lr)*256 + ks*32 + lk*8]);
                        #pragma unroll
                        for (int rt = 0; rt < 2; ++rt)
                            acc[tt][rt] = __builtin_amdgcn_mfma_f32_16x16x32_bf16(afr[rt], b, acc[tt][rt], 0, 0, 0);
                    } else {
                        short8 bh = *(const short8*)(&WSPH[((ct-2)*16+lr)*256 + ks*32 + lk*8]);
                        short8 bl = *(const short8*)(&WSPL[((ct-2)*16+lr)*256 + ks*32 + lk*8]);
                        #pragma unroll
                        for (int rt = 0; rt < 2; ++rt) {
                            acc[tt][rt] = __builtin_amdgcn_mfma_f32_16x16x32_bf16(afr[rt], bh, acc[tt][rt], 0, 0, 0);
                            acc[tt][rt] = __builtin_amdgcn_mfma_f32_16x16x32_bf16(afr[rt], bl, acc[tt][rt], 0, 0, 0);
                        }
                    }
                }
            }
        }
        float* sp = out + (size_t)BATCH*32;
        #pragma unroll
        for (int tt = 0; tt < 3; ++tt) {
            if (tt < nt) {
                int ct = wv + tt*4;
                #pragma unroll
                for (int rt = 0; rt < 2; ++rt) {
                    int rowb = row0 + rt*16 + lk*4;
                    #pragma unroll
                    for (int r = 0; r < 4; ++r) {
                        float vv = acc[tt][rt][r];
                        if (ct < 2) out[(size_t)(rowb+r)*32  + ct*16 + lr]     = vv;
                        else        sp[(size_t)(rowb+r)*128 + (ct-2)*16 + lr] = vv;
                    }
                }
            }
        }
    }
}

extern "C" void kernel_launch(void* const* d_in, const int* in_sizes, int n_in,
                              void* d_out, int out_size, void* d_ws, size_t ws_size,
                              hipStream_t stream)
{
    const float* inpt  = (const float*)d_in[0];
    const float* state = (const float*)d_in[1];
    const float* X   = (const float*)d_in[2];
    const float* Y1  = (const float*)d_in[3];
    const float* X3  = (const float*)d_in[4];
    const float* Y3  = (const float*)d_in[5];
    const float* Z3  = (const float*)d_in[6];
    const float* B2  = (const float*)d_in[7];
    const float* C2  = (const float*)d_in[8];
    const float* D21 = (const float*)d_in[9];
    const float* D12 = (const float*)d_in[10];
    float* ws  = (float*)d_ws;
    float* out = (float*)d_out;

    kF_abc<<<1, 1024, 0, stream>>>(X3, Y3, Z3, ws);
    kS_gj64g<<<1, 256, 0, stream>>>(ws, WS_RC, 64, WS_RC, 64);   // Rinv
    k_vecr<<<80, 256, 0, stream>>>(B2, C2, D21, D12, ws);
    k_T<<<80, 256, 0, stream>>>(ws);
    k_H<<<(NTOT*NTOT + 255)/256, 256, 0, stream>>>(X, C2, D21, ws);
    k_extract<<<128, 256, 0, stream>>>(Y1, C2, D21, D12, B2, ws);
    kS_gj64g<<<1, 256, 0, stream>>>(ws, WS_E, 128, SC_AI, 64);   // Ai
    kS_PQ<<<32, 256, 0, stream>>>(ws);                           // P, Q
    kS_S<<<16, 256, 0, stream>>>(ws);                            // S
    kS_gj64g<<<1, 256, 0, stream>>>(ws, SC_S, 64, SC_S, 64);     // Si
    kS_R<<<16, 256, 0, stream>>>(ws);                            // R2; bl
    kS_TL<<<16, 256, 0, stream>>>(ws);                           // tl, tr, br
    k_Wsp<<<128, 256, 0, stream>>>(ws);
    k_batch<<<BATCH/ROWS, 256, 0, stream>>>(inpt, state, ws, out);
}

// Round 21
// 293.193 us; speedup vs baseline: 1.1377x; 1.1377x over previous
//
#include <hip/hip_runtime.h>
#include <math.h>

#define BATCH 131072
#define NTOT 320

typedef __attribute__((ext_vector_type(8))) short short8;
typedef __attribute__((ext_vector_type(4))) float f32x4;

// ---- ws layout (float offsets) ----
#define WS_D22   0          // 32*64
#define WS_VR    2048       // 320*64
#define WS_T     22528      // 320*64
#define WS_H     43008      // 320*320
#define WS_E     145408     // 128*128
#define WS_EINV  161792     // 128*128
#define WS_WEXT  178176     // 128*256
#define WS_D11   210944     // 64*64
#define WS_ILAM  215040     // 64
#define WS_BFU   215104     // ushort region below
#define U_WATH 0
#define U_WATL 16384
#define U_WOT  32768
#define U_WSPH 40960
#define U_WSPL 73728
// transient scratch inside WS_H:
#define WS_RC   (WS_H + 2048)   // 64*64  R_cal -> Rinv (in place)
#define SC_AI   (WS_H)          // 64*64
#define SC_P    (WS_H + 4096)
#define SC_S    (WS_H + 8192)
#define SC_Q    (WS_H + 12288)
#define SC_R    (WS_H + 16384)

__device__ inline unsigned short f2bf(float x){
    unsigned u = __builtin_bit_cast(unsigned, x);
    u += 0x7FFFu + ((u >> 16) & 1u);
    return (unsigned short)(u >> 16);
}
__device__ inline float bf2f(unsigned short h){
    unsigned u = ((unsigned)h) << 16;
    return __builtin_bit_cast(float, u);
}
__device__ inline float r_diag(int j) {
    return (j < 16 || j == 39) ? 100000.0f : 0.001f;
}

// ---------------------------------------------------------------------------
// kF_abc: fused M -> GJ32 -> D22 -> R_cal.  1 block, 1024 threads. (R20 form)
// ---------------------------------------------------------------------------
__global__ __launch_bounds__(1024) void kF_abc(
    const float* __restrict__ X3, const float* __restrict__ Y3,
    const float* __restrict__ Z3, float* __restrict__ ws)
{
    __shared__ float Msh[32*33];
    __shared__ float A32[32*33];
    __shared__ float D22s[2048];
    const int t = threadIdx.x;
    const int i = t >> 5, j = t & 31;
    {
        float s = 0.f;
        for (int k = 0; k < 32; ++k)
            s += X3[k*32+i]*X3[k*32+j] + Z3[k*32+i]*Z3[k*32+j];
        s += Y3[i*32+j] - Y3[j*32+i];
        if (i == j) s += 0.001f;
        Msh[i*33+j] = s;
        A32[i*33+j] = s + (i == j ? 1.f : 0.f);
    }
    __syncthreads();
    for (int k = 0; k < 32; ++k) {
        float ip = 1.f / A32[k*33+k];
        float f  = A32[i*33+k];
        float pj = A32[k*33+j];
        __syncthreads();
        float nv;
        if (i == k) nv = (j == k) ? ip : pj*ip;
        else        nv = (j == k) ? (-f*ip) : (A32[i*33+j] - f*ip*pj);
        A32[i*33+j] = nv;
        __syncthreads();
    }
    for (int idx = t; idx < 2048; idx += 1024) {
        int i2 = idx >> 6, j2 = idx & 63;
        float s = 0.f;
        if (j2 < 32) {
            for (int k = 0; k < 32; ++k) {
                float im = (k == j2 ? 1.f : 0.f) - Msh[k*33+j2];
                s += A32[i2*33+k]*im;
            }
        } else {
            int jj = j2 - 32;
            for (int k = 0; k < 32; ++k) s += A32[i2*33+k]*Z3[jj*32+k];
            s *= -2.f;
        }
        float d22 = s * sqrtf(r_diag(j2)) * 0.31622776601683794f;
        D22s[idx] = d22;
        ws[WS_D22 + idx] = d22;
    }
    __syncthreads();
    for (int idx = t; idx < 4096; idx += 1024) {
        int i2 = idx >> 6, j2 = idx & 63;
        float s = 0.f;
        for (int k = 0; k < 32; ++k) s += D22s[k*64+i2]*D22s[k*64+j2];
        float v = -10.f*s;
        if (i2 == j2) v += r_diag(i2);
        ws[WS_RC + idx] = v;
    }
}

// ---------------------------------------------------------------------------
// GJ64 generic: 256 threads, q-uniform, Ar[16] register (PROVEN shape).
// ---------------------------------------------------------------------------
__global__ __launch_bounds__(256) void kS_gj64g(float* __restrict__ ws,
    int srcOff, int srcStride, int dstOff, int dstStride)
{
    __shared__ float piv[2][64];
    __shared__ float fcol[2][64];
    __shared__ float ipd[2];
    const int t = threadIdx.x;
    const int q = t >> 6;
    const int i = t & 63;
    const int c0 = q*16;

    float Ar[16];
    {
        const float* Rin = ws + srcOff + i*srcStride + c0;
        #pragma unroll
        for (int jj = 0; jj < 4; ++jj) {
            float4 v = *(const float4*)(Rin + jj*4);
            Ar[jj*4+0]=v.x; Ar[jj*4+1]=v.y; Ar[jj*4+2]=v.z; Ar[jj*4+3]=v.w;
        }
    }
    for (int k = 0; k < 64; ++k) {
        const int b  = k & 1;
        const int kq = k >> 4;
        const int kj = k & 15;
        float f_own = Ar[0];
        #pragma unroll
        for (int jj = 1; jj < 16; ++jj) f_own = (jj == kj) ? Ar[jj] : f_own;
        if (q == kq) fcol[b][i] = f_own;
        if (i == k) {
            #pragma unroll
            for (int jj = 0; jj < 4; ++jj) {
                float4 v;
                v.x = Ar[jj*4+0] + ((q==kq && jj*4+0==kj) ? 1.f : 0.f);
                v.y = Ar[jj*4+1] + ((q==kq && jj*4+1==kj) ? 1.f : 0.f);
                v.z = Ar[jj*4+2] + ((q==kq && jj*4+2==kj) ? 1.f : 0.f);
                v.w = Ar[jj*4+3] + ((q==kq && jj*4+3==kj) ? 1.f : 0.f);
                *(float4*)(&piv[b][c0 + jj*4]) = v;
            }
            if (q == kq) ipd[b] = 1.f / f_own;
        }
        __syncthreads();
        const float ipv = ipd[b];
        if (i == k) {
            #pragma unroll
            for (int jj = 0; jj < 16; ++jj)
                Ar[jj] = (q==kq && jj==kj) ? ipv : Ar[jj]*ipv;
        } else {
            const float g = fcol[b][i] * ipv;
            #pragma unroll
            for (int jj = 0; jj < 4; ++jj) {
                float4 pv = *(const float4*)(&piv[b][c0 + jj*4]);
                Ar[jj*4+0] -= g*pv.x;
                Ar[jj*4+1] -= g*pv.y;
                Ar[jj*4+2] -= g*pv.z;
                Ar[jj*4+3] -= g*pv.w;
            }
        }
    }
    {
        float* Rout = ws + dstOff + i*dstStride + c0;
        #pragma unroll
        for (int jj = 0; jj < 4; ++jj) {
            float4 v;
            v.x=Ar[jj*4+0]; v.y=Ar[jj*4+1]; v.z=Ar[jj*4+2]; v.w=Ar[jj*4+3];
            *(float4*)(Rout + jj*4) = v;
        }
    }
}

// ---------------------------------------------------------------------------
// vec_r, T (80 blocks each; proven)
// ---------------------------------------------------------------------------
__global__ __launch_bounds__(256) void k_vecr(
    const float* __restrict__ B2, const float* __restrict__ C2,
    const float* __restrict__ D21, const float* __restrict__ D12,
    float* __restrict__ ws)
{
    int idx = blockIdx.x*256 + threadIdx.x;
    if (idx >= 320*64) return;
    int i = idx >> 6, j = idx & 63;
    const float* D22 = ws + WS_D22;
    float v;
    if (i < 128) {
        float s = 0.f;
        for (int k = 0; k < 32; ++k) s += C2[k*128+i]*D22[k*64+j];
        v = -10.f*s;
    } else if (i < 192) {
        int ii = i - 128;
        float s = 0.f;
        for (int k = 0; k < 32; ++k) s += D21[k*64+ii]*D22[k*64+j];
        v = -10.f*s - D12[ii*64+j];
    } else {
        v = B2[(i-192)*64 + j];
    }
    ws[WS_VR+idx] = v;
}

__global__ __launch_bounds__(256) void k_T(float* __restrict__ ws)
{
    int idx = blockIdx.x*256 + threadIdx.x;
    if (idx >= 320*64) return;
    int i = idx >> 6, j = idx & 63;
    const float* VR = ws + WS_VR + i*64;
    const float* RC = ws + WS_RC;
    float s = 0.f;
    for (int k = 0; k < 64; ++k) s += VR[k] * RC[k*64+j];
    ws[WS_T+idx] = s;
}

// ---------------------------------------------------------------------------
// K2: H
// ---------------------------------------------------------------------------
__global__ void k_H(const float* __restrict__ X, const float* __restrict__ C2,
                    const float* __restrict__ D21, float* __restrict__ ws)
{
    int idx = blockIdx.x*256 + threadIdx.x;
    if (idx >= NTOT*NTOT) return;
    int i = idx / NTOT, j = idx % NTOT;
    float s = (i == j) ? 0.001f : 0.f;
    for (int k = 0; k < NTOT; ++k) s += X[k*NTOT+i]*X[k*NTOT+j];
    const float* T  = ws + WS_T;
    const float* vr = ws + WS_VR;
    float s2 = 0.f;
    for (int k = 0; k < 64; ++k) s2 += T[i*64+k]*vr[j*64+k];
    s += s2;
    if (i < 192 && j < 192) {
        float s3 = 0.f;
        for (int k = 0; k < 32; ++k) {
            float qi = (i < 128) ? C2[k*128+i] : D21[k*64 + (i-128)];
            float qj = (j < 128) ? C2[k*128+j] : D21[k*64 + (j-128)];
            s3 += qi*qj;
        }
        s += 10.f*s3;
    }
    ws[WS_H + idx] = s;
}

// ---------------------------------------------------------------------------
// K3: extract
// ---------------------------------------------------------------------------
__global__ void k_extract(const float* __restrict__ Y1, const float* __restrict__ C2,
                          const float* __restrict__ D21, const float* __restrict__ D12,
                          const float* __restrict__ B2, float* __restrict__ ws)
{
    const float* H = ws + WS_H;
    unsigned short* bfb = (unsigned short*)(ws + WS_BFU);
    int tid = blockIdx.x*blockDim.x + threadIdx.x;
    int nth = gridDim.x*blockDim.x;
    for (int idx = tid; idx < 128*128; idx += nth) {
        int i = idx >> 7, j = idx & 127;
        ws[WS_E+idx] = 0.5f*(H[i*320+j] + H[(192+i)*320 + 192+j] + Y1[i*128+j] - Y1[j*128+i]);
    }
    for (int i = tid; i < 64; i += nth)
        ws[WS_ILAM+i] = 2.0f / H[(128+i)*320 + 128+i];
    for (int idx = tid; idx < 64*64; idx += nth) {
        int i = idx >> 6, j = idx & 63;
        ws[WS_D11+idx] = (j < i) ? -H[(128+i)*320 + 128+j] : 0.f;
    }
    for (int idx = tid; idx < 128*256; idx += nth) {
        int m = idx >> 8, k = idx & 255;
        ws[WS_WEXT+idx] = (k < 192) ? H[(192+m)*320 + k] : B2[m*64 + (k-192)];
    }
    for (int idx = tid; idx < 64*256; idx += nth) {
        int j = idx >> 8, k = idx & 255;
        float v;
        if (k < 128)      v = -H[(128+j)*320 + k];
        else if (k < 192) v = 0.f;
        else              v = D12[j*64 + (k-192)];
        unsigned short hi = f2bf(v);
        bfb[U_WATH+idx] = hi;
        bfb[U_WATL+idx] = f2bf(v - bf2f(hi));
    }
    const float* D22 = ws + WS_D22;
    for (int idx = tid; idx < 32*256; idx += nth) {
        int c = idx >> 8, k = idx & 255;
        float v;
        if (k < 128)      v = C2[c*128+k];
        else if (k < 192) v = D21[c*64 + (k-128)];
        else              v = D22[c*64 + (k-192)];
        bfb[U_WOT+idx] = f2bf(v);
    }
}

// ---------------------------------------------------------------------------
// Schur GEMM pieces. kS_PQ merges P and Q (both depend only on Ai).
// ---------------------------------------------------------------------------
__global__ __launch_bounds__(256) void kS_PQ(float* __restrict__ ws)
{
    int gid = blockIdx.x*256 + threadIdx.x;
    const float* E  = ws + WS_E;
    if (gid < 4096) {                 // P = Ai @ B
        int i = gid >> 6, j = gid & 63;
        const float* AI = ws + SC_AI + i*64;
        float s = 0.f;
        for (int k = 0; k < 64; ++k) s += AI[k] * E[k*128 + 64 + j];
        ws[SC_P + gid] = s;
    } else {                          // Q = C @ Ai
        int idx = gid - 4096;
        int i = idx >> 6, j = idx & 63;
        const float* C = E + (64+i)*128;
        const float* AI = ws + SC_AI;
        float s = 0.f;
        for (int k = 0; k < 64; ++k) s += C[k] * AI[k*64 + j];
        ws[SC_Q + idx] = s;
    }
}
__global__ __launch_bounds__(256) void kS_S(float* __restrict__ ws)
{
    int idx = blockIdx.x*256 + threadIdx.x;
    int i = idx >> 6, j = idx & 63;
    const float* E = ws + WS_E;
    const float* C = E + (64+i)*128;
    const float* P = ws + SC_P;
    float s = E[(64+i)*128 + 64 + j];
    for (int k = 0; k < 64; ++k) s -= C[k] * P[k*64 + j];
    ws[SC_S + idx] = s;
}
__global__ __launch_bounds__(256) void kS_R(float* __restrict__ ws)
{
    int idx = blockIdx.x*256 + threadIdx.x;
    int i = idx >> 6, j = idx & 63;
    const float* Si = ws + SC_S + i*64;
    const float* Q  = ws + SC_Q;
    float s = 0.f;
    for (int k = 0; k < 64; ++k) s += Si[k] * Q[k*64 + j];
    ws[SC_R + idx] = s;
    ws[WS_EINV + (64+i)*128 + j] = -s;
}
__global__ __launch_bounds__(256) void kS_TL(float* __restrict__ ws)
{
    int idx = blockIdx.x*256 + threadIdx.x;
    int i = idx >> 6, j = idx & 63;
    const float* P  = ws + SC_P + i*64;
    const float* R2 = ws + SC_R;
    const float* Si = ws + SC_S;
    float s1 = ws[SC_AI + idx];
    float s2 = 0.f;
    for (int k = 0; k < 64; ++k) {
        s1 += P[k] * R2[k*64 + j];
        s2 += P[k] * Si[k*64 + j];
    }
    ws[WS_EINV + i*128 + j]           = s1;
    ws[WS_EINV + i*128 + 64 + j]      = -s2;
    ws[WS_EINV + (64+i)*128 + 64 + j] = Si[i*64 + j];
}

// ---------------------------------------------------------------------------
// K5: Wsp
// ---------------------------------------------------------------------------
__global__ __launch_bounds__(256) void k_Wsp(float* __restrict__ ws)
{
    int i = blockIdx.x;
    int k = threadIdx.x;
    const float* Einv = ws + WS_EINV + i*128;
    const float* WexT = ws + WS_WEXT;
    unsigned short* bfb = (unsigned short*)(ws + WS_BFU);
    float s = 0.f;
    for (int m = 0; m < 128; ++m) s += Einv[m] * WexT[m*256 + k];
    unsigned short hi = f2bf(s);
    bfb[U_WSPH + i*256 + k] = hi;
    bfb[U_WSPL + i*256 + k] = f2bf(s - bf2f(hi));
}

// ---------------------------------------------------------------------------
// K6: batch kernel — R19-EXACT ROWS=64 form (116us, Occ 38%; R20's ROWS=32
// regressed to 168us: per-block fixed overhead (D11t staging + weight loads)
// amortized over half the rows. Occupancy is not the binding constraint.)
// ---------------------------------------------------------------------------
__global__ __launch_bounds__(256, 4) void k_batch(
    const float* __restrict__ inpt, const float* __restrict__ state,
    const float* __restrict__ ws, float* __restrict__ out)
{
    __shared__ unsigned short zsh[64*256];    // 32768 B
    __shared__ unsigned short D11t[64*64];    // 8192 B (transposed, bf16)
    const int t = threadIdx.x;
    const int row0 = blockIdx.x * 64;
    const unsigned short* bfb = (const unsigned short*)(ws + WS_BFU);

    for (int idx = t; idx < 64*16; idx += 256) {
        int r = idx >> 4, c = idx & 15;
        const float4* p = (const float4*)(state + (size_t)(row0+r)*128 + c*8);
        float4 f0 = p[0], f1 = p[1];
        short8 h;
        h[0]=(short)f2bf(f0.x); h[1]=(short)f2bf(f0.y); h[2]=(short)f2bf(f0.z); h[3]=(short)f2bf(f0.w);
        h[4]=(short)f2bf(f1.x); h[5]=(short)f2bf(f1.y); h[6]=(short)f2bf(f1.z); h[7]=(short)f2bf(f1.w);
        *(short8*)(&zsh[r*256 + ((c ^ (r&7)) << 3)]) = h;
    }
    for (int idx = t; idx < 64*8; idx += 256) {
        int r = idx >> 3, cl = idx & 7, c = 24 + cl;
        const float4* p = (const float4*)(inpt + (size_t)(row0+r)*64 + cl*8);
        float4 f0 = p[0], f1 = p[1];
        short8 h;
        h[0]=(short)f2bf(f0.x); h[1]=(short)f2bf(f0.y); h[2]=(short)f2bf(f0.z); h[3]=(short)f2bf(f0.w);
        h[4]=(short)f2bf(f1.x); h[5]=(short)f2bf(f1.y); h[6]=(short)f2bf(f1.z); h[7]=(short)f2bf(f1.w);
        *(short8*)(&zsh[r*256 + ((c ^ (r&7)) << 3)]) = h;
    }
    for (int idx = t; idx < 4096; idx += 256) {
        int j = idx >> 6, i = idx & 63;
        float v = (i == j) ? ws[WS_ILAM + j] : ws[WS_D11 + i*64 + j];
        D11t[idx] = f2bf(v);
    }
    __syncthreads();

    const int wv = t >> 6, lane = t & 63, lr = lane & 15, lk = lane >> 4;

    {
        const unsigned short* WATH = bfb + U_WATH;
        const unsigned short* WATL = bfb + U_WATL;
        f32x4 acc1[4] = {};
        const int ks1[6] = {0,1,2,3,6,7};
        #pragma unroll
        for (int s = 0; s < 6; ++s) {
            int ks = ks1[s];
            short8 bh = *(const short8*)(&WATH[(wv*16+lr)*256 + ks*32 + lk*8]);
            short8 bl = *(const short8*)(&WATL[(wv*16+lr)*256 + ks*32 + lk*8]);
            #pragma unroll
            for (int rt = 0; rt < 4; ++rt) {
                int row = rt*16 + lr, c = ks*4 + lk;
                short8 a = *(const short8*)(&zsh[row*256 + ((c ^ (row&7)) << 3)]);
                acc1[rt] = __builtin_amdgcn_mfma_f32_16x16x32_bf16(a, bh, acc1[rt], 0, 0, 0);
                acc1[rt] = __builtin_amdgcn_mfma_f32_16x16x32_bf16(a, bl, acc1[rt], 0, 0, 0);
            }
        }
        __syncthreads();
        const int ac = wv*16 + lr;
        const int cch = 16 + (ac >> 3), coff = ac & 7;
        #pragma unroll
        for (int rt = 0; rt < 4; ++rt)
            #pragma unroll
            for (int r = 0; r < 4; ++r) {
                int row = rt*16 + lk*4 + r;
                zsh[row*256 + ((cch ^ (row&7)) << 3) + coff] = f2bf(acc1[rt][r]);
            }
    }
    __syncthreads();

    {
        const int r  = wv*16 + (lane >> 2);
        const int qq = lane & 3;
        float acc[16];
        #pragma unroll
        for (int s = 0; s < 16; ++s) {
            int i = qq*16 + s;
            int cch = 16 + (i >> 3);
            acc[s] = bf2f(zsh[r*256 + ((cch ^ (r&7)) << 3) + (i & 7)]);
        }
        float wloc[16];
        #pragma unroll
        for (int j = 0; j < 64; ++j) {
            float diag = bf2f(D11t[j*64 + j]);
            float v = acc[j & 15];
            float x = v * diag;
            float e = __expf(2.f*x);
            float wc = 1.f - __fdividef(2.f, e + 1.f);
            int src = (lane & 0x3C) | (j >> 4);
            float wj = __shfl(wc, src, 64);
            if ((j >> 4) == qq) wloc[j & 15] = wj;
            #pragma unroll
            for (int s = 0; s < 16; ++s)
                acc[s] += wj * bf2f(D11t[j*64 + qq*16 + s]);
        }
        #pragma unroll
        for (int cc = 0; cc < 2; ++cc) {
            int ch = 16 + qq*2 + cc;
            short8 h;
            #pragma unroll
            for (int e2 = 0; e2 < 8; ++e2) h[e2] = (short)f2bf(wloc[cc*8 + e2]);
            *(short8*)(&zsh[r*256 + ((ch ^ (r&7)) << 3)]) = h;
        }
    }
    __syncthreads();

    {
        const unsigned short* WOT  = bfb + U_WOT;
        const unsigned short* WSPH = bfb + U_WSPH;
        const unsigned short* WSPL = bfb + U_WSPL;
        f32x4 acc[3][4] = {};
        const int nt = (wv < 2) ? 3 : 2;
        #pragma unroll
        for (int ks = 0; ks < 8; ++ks) {
            short8 afr[4];
            #pragma unroll
            for (int rt = 0; rt < 4; ++rt) {
                int row = rt*16 + lr, c = ks*4 + lk;
                afr[rt] = *(const short8*)(&zsh[row*256 + ((c ^ (row&7)) << 3)]);
            }
            #pragma unroll
            for (int tt = 0; tt < 3; ++tt) {
                if (tt < nt) {
                    int ct = wv + tt*4;
                    if (ct < 2) {
                        short8 b = *(const short8*)(&WOT[(ct*16+lr)*256 + ks*32 + lk*8]);
                        #pragma unroll
                        for (int rt = 0; rt < 4; ++rt)
                            acc[tt][rt] = __builtin_amdgcn_mfma_f32_16x16x32_bf16(afr[rt], b, acc[tt][rt], 0, 0, 0);
                    } else {
                        short8 bh = *(const short8*)(&WSPH[((ct-2)*16+lr)*256 + ks*32 + lk*8]);
                        short8 bl = *(const short8*)(&WSPL[((ct-2)*16+lr)*256 + ks*32 + lk*8]);
                        #pragma unroll
                        for (int rt = 0; rt < 4; ++rt) {
                            acc[tt][rt] = __builtin_amdgcn_mfma_f32_16x16x32_bf16(afr[rt], bh, acc[tt][rt], 0, 0, 0);
                            acc[tt][rt] = __builtin_amdgcn_mfma_f32_16x16x32_bf16(afr[rt], bl, acc[tt][rt], 0, 0, 0);
                        }
                    }
                }
            }
        }
        float* sp = out + (size_t)BATCH*32;
        #pragma unroll
        for (int tt = 0; tt < 3; ++tt) {
            if (tt < nt) {
                int ct = wv + tt*4;
                #pragma unroll
                for (int rt = 0; rt < 4; ++rt) {
                    int rowb = row0 + rt*16 + lk*4;
                    #pragma unroll
                    for (int r = 0; r < 4; ++r) {
                        float vv = acc[tt][rt][r];
                        if (ct < 2) out[(size_t)(rowb+r)*32  + ct*16 + lr]     = vv;
                        else        sp[(size_t)(rowb+r)*128 + (ct-2)*16 + lr] = vv;
                    }
                }
            }
        }
    }
}

extern "C" void kernel_launch(void* const* d_in, const int* in_sizes, int n_in,
                              void* d_out, int out_size, void* d_ws, size_t ws_size,
                              hipStream_t stream)
{
    const float* inpt  = (const float*)d_in[0];
    const float* state = (const float*)d_in[1];
    const float* X   = (const float*)d_in[2];
    const float* Y1  = (const float*)d_in[3];
    const float* X3  = (const float*)d_in[4];
    const float* Y3  = (const float*)d_in[5];
    const float* Z3  = (const float*)d_in[6];
    const float* B2  = (const float*)d_in[7];
    const float* C2  = (const float*)d_in[8];
    const float* D21 = (const float*)d_in[9];
    const float* D12 = (const float*)d_in[10];
    float* ws  = (float*)d_ws;
    float* out = (float*)d_out;

    kF_abc<<<1, 1024, 0, stream>>>(X3, Y3, Z3, ws);
    kS_gj64g<<<1, 256, 0, stream>>>(ws, WS_RC, 64, WS_RC, 64);   // Rinv
    k_vecr<<<80, 256, 0, stream>>>(B2, C2, D21, D12, ws);
    k_T<<<80, 256, 0, stream>>>(ws);
    k_H<<<(NTOT*NTOT + 255)/256, 256, 0, stream>>>(X, C2, D21, ws);
    k_extract<<<128, 256, 0, stream>>>(Y1, C2, D21, D12, B2, ws);
    kS_gj64g<<<1, 256, 0, stream>>>(ws, WS_E, 128, SC_AI, 64);   // Ai
    kS_PQ<<<32, 256, 0, stream>>>(ws);                           // P, Q
    kS_S<<<16, 256, 0, stream>>>(ws);                            // S
    kS_gj64g<<<1, 256, 0, stream>>>(ws, SC_S, 64, SC_S, 64);     // Si
    kS_R<<<16, 256, 0, stream>>>(ws);                            // R2; bl
    kS_TL<<<16, 256, 0, stream>>>(ws);                           // tl, tr, br
    k_Wsp<<<128, 256, 0, stream>>>(ws);
    k_batch<<<BATCH/64, 256, 0, stream>>>(inpt, state, ws, out);
}

// Round 22
// 290.245 us; speedup vs baseline: 1.1493x; 1.0102x over previous
//
#include <hip/hip_runtime.h>
#include <math.h>

#define BATCH 131072
#define NTOT 320

typedef __attribute__((ext_vector_type(8))) short short8;
typedef __attribute__((ext_vector_type(4))) float f32x4;

// ---- ws layout (float offsets) ----
#define WS_D22   0          // 32*64
#define WS_VR    2048       // 320*64
#define WS_T     22528      // 320*64
#define WS_H     43008      // 320*320
#define WS_E     145408     // 128*128
#define WS_EINV  161792     // 128*128
#define WS_WEXT  178176     // 128*256
#define WS_D11   210944     // 64*64
#define WS_ILAM  215040     // 64
#define WS_BFU   215104     // ushort region below
#define U_WATH 0
#define U_WATL 16384
#define U_WOT  32768
#define U_WSPH 40960
#define U_WSPL 73728
// transient scratch inside WS_H:
#define WS_RC   (WS_H + 2048)   // 64*64  R_cal -> Rinv (in place)
#define SC_AI   (WS_H)          // 64*64
#define SC_P    (WS_H + 4096)
#define SC_S    (WS_H + 8192)
#define SC_Q    (WS_H + 12288)
#define SC_R    (WS_H + 16384)

__device__ inline unsigned short f2bf(float x){
    unsigned u = __builtin_bit_cast(unsigned, x);
    u += 0x7FFFu + ((u >> 16) & 1u);
    return (unsigned short)(u >> 16);
}
__device__ inline float bf2f(unsigned short h){
    unsigned u = ((unsigned)h) << 16;
    return __builtin_bit_cast(float, u);
}
__device__ inline float r_diag(int j) {
    return (j < 16 || j == 39) ? 100000.0f : 0.001f;
}

// ---------------------------------------------------------------------------
// kF_abc: fused M -> GJ32 -> D22 -> R_cal.  1 block, 1024 threads. (proven)
// ---------------------------------------------------------------------------
__global__ __launch_bounds__(1024) void kF_abc(
    const float* __restrict__ X3, const float* __restrict__ Y3,
    const float* __restrict__ Z3, float* __restrict__ ws)
{
    __shared__ float Msh[32*33];
    __shared__ float A32[32*33];
    __shared__ float D22s[2048];
    const int t = threadIdx.x;
    const int i = t >> 5, j = t & 31;
    {
        float s = 0.f;
        for (int k = 0; k < 32; ++k)
            s += X3[k*32+i]*X3[k*32+j] + Z3[k*32+i]*Z3[k*32+j];
        s += Y3[i*32+j] - Y3[j*32+i];
        if (i == j) s += 0.001f;
        Msh[i*33+j] = s;
        A32[i*33+j] = s + (i == j ? 1.f : 0.f);
    }
    __syncthreads();
    for (int k = 0; k < 32; ++k) {
        float ip = 1.f / A32[k*33+k];
        float f  = A32[i*33+k];
        float pj = A32[k*33+j];
        __syncthreads();
        float nv;
        if (i == k) nv = (j == k) ? ip : pj*ip;
        else        nv = (j == k) ? (-f*ip) : (A32[i*33+j] - f*ip*pj);
        A32[i*33+j] = nv;
        __syncthreads();
    }
    for (int idx = t; idx < 2048; idx += 1024) {
        int i2 = idx >> 6, j2 = idx & 63;
        float s = 0.f;
        if (j2 < 32) {
            for (int k = 0; k < 32; ++k) {
                float im = (k == j2 ? 1.f : 0.f) - Msh[k*33+j2];
                s += A32[i2*33+k]*im;
            }
        } else {
            int jj = j2 - 32;
            for (int k = 0; k < 32; ++k) s += A32[i2*33+k]*Z3[jj*32+k];
            s *= -2.f;
        }
        float d22 = s * sqrtf(r_diag(j2)) * 0.31622776601683794f;
        D22s[idx] = d22;
        ws[WS_D22 + idx] = d22;
    }
    __syncthreads();
    for (int idx = t; idx < 4096; idx += 1024) {
        int i2 = idx >> 6, j2 = idx & 63;
        float s = 0.f;
        for (int k = 0; k < 32; ++k) s += D22s[k*64+i2]*D22s[k*64+j2];
        float v = -10.f*s;
        if (i2 == j2) v += r_diag(i2);
        ws[WS_RC + idx] = v;
    }
}

// ---------------------------------------------------------------------------
// GJ64 generic: 256 threads, q-uniform, Ar[16] register (PROVEN shape).
// ---------------------------------------------------------------------------
__global__ __launch_bounds__(256) void kS_gj64g(float* __restrict__ ws,
    int srcOff, int srcStride, int dstOff, int dstStride)
{
    __shared__ float piv[2][64];
    __shared__ float fcol[2][64];
    __shared__ float ipd[2];
    const int t = threadIdx.x;
    const int q = t >> 6;
    const int i = t & 63;
    const int c0 = q*16;

    float Ar[16];
    {
        const float* Rin = ws + srcOff + i*srcStride + c0;
        #pragma unroll
        for (int jj = 0; jj < 4; ++jj) {
            float4 v = *(const float4*)(Rin + jj*4);
            Ar[jj*4+0]=v.x; Ar[jj*4+1]=v.y; Ar[jj*4+2]=v.z; Ar[jj*4+3]=v.w;
        }
    }
    for (int k = 0; k < 64; ++k) {
        const int b  = k & 1;
        const int kq = k >> 4;
        const int kj = k & 15;
        float f_own = Ar[0];
        #pragma unroll
        for (int jj = 1; jj < 16; ++jj) f_own = (jj == kj) ? Ar[jj] : f_own;
        if (q == kq) fcol[b][i] = f_own;
        if (i == k) {
            #pragma unroll
            for (int jj = 0; jj < 4; ++jj) {
                float4 v;
                v.x = Ar[jj*4+0] + ((q==kq && jj*4+0==kj) ? 1.f : 0.f);
                v.y = Ar[jj*4+1] + ((q==kq && jj*4+1==kj) ? 1.f : 0.f);
                v.z = Ar[jj*4+2] + ((q==kq && jj*4+2==kj) ? 1.f : 0.f);
                v.w = Ar[jj*4+3] + ((q==kq && jj*4+3==kj) ? 1.f : 0.f);
                *(float4*)(&piv[b][c0 + jj*4]) = v;
            }
            if (q == kq) ipd[b] = 1.f / f_own;
        }
        __syncthreads();
        const float ipv = ipd[b];
        if (i == k) {
            #pragma unroll
            for (int jj = 0; jj < 16; ++jj)
                Ar[jj] = (q==kq && jj==kj) ? ipv : Ar[jj]*ipv;
        } else {
            const float g = fcol[b][i] * ipv;
            #pragma unroll
            for (int jj = 0; jj < 4; ++jj) {
                float4 pv = *(const float4*)(&piv[b][c0 + jj*4]);
                Ar[jj*4+0] -= g*pv.x;
                Ar[jj*4+1] -= g*pv.y;
                Ar[jj*4+2] -= g*pv.z;
                Ar[jj*4+3] -= g*pv.w;
            }
        }
    }
    {
        float* Rout = ws + dstOff + i*dstStride + c0;
        #pragma unroll
        for (int jj = 0; jj < 4; ++jj) {
            float4 v;
            v.x=Ar[jj*4+0]; v.y=Ar[jj*4+1]; v.z=Ar[jj*4+2]; v.w=Ar[jj*4+3];
            *(float4*)(Rout + jj*4) = v;
        }
    }
}

// ---------------------------------------------------------------------------
// k_vecrT: fused vec_r + T.  80 blocks x 256; block handles 4 rows.
// vr row staged in LDS, consumed immediately; VR also written for k_H.
// ---------------------------------------------------------------------------
__global__ __launch_bounds__(256) void k_vecrT(
    const float* __restrict__ B2, const float* __restrict__ C2,
    const float* __restrict__ D21, const float* __restrict__ D12,
    float* __restrict__ ws)
{
    __shared__ float vrsh[4*64];
    const int t = threadIdx.x;
    const int r = t >> 6, k = t & 63;
    const int i = blockIdx.x*4 + r;
    const float* D22 = ws + WS_D22;
    float v;
    if (i < 128) {
        float s = 0.f;
        for (int kk = 0; kk < 32; ++kk) s += C2[kk*128+i]*D22[kk*64+k];
        v = -10.f*s;
    } else if (i < 192) {
        int ii = i - 128;
        float s = 0.f;
        for (int kk = 0; kk < 32; ++kk) s += D21[kk*64+ii]*D22[kk*64+k];
        v = -10.f*s - D12[ii*64+k];
    } else {
        v = B2[(i-192)*64 + k];
    }
    vrsh[r*64 + k] = v;
    ws[WS_VR + i*64 + k] = v;
    __syncthreads();
    const float* RC = ws + WS_RC;
    float s = 0.f;
    for (int kk = 0; kk < 64; ++kk) s += vrsh[r*64 + kk] * RC[kk*64 + k];
    ws[WS_T + i*64 + k] = s;
}

// ---------------------------------------------------------------------------
// K2: H — SYMMETRIC (H = X^TX + eps I + vr Rinv vr^T - vq Q vq^T; all terms
// symmetric). Compute i<=j only, mirror-write. Halves the 320-deep k-loops.
// ---------------------------------------------------------------------------
__global__ void k_H(const float* __restrict__ X, const float* __restrict__ C2,
                    const float* __restrict__ D21, float* __restrict__ ws)
{
    int idx = blockIdx.x*256 + threadIdx.x;
    if (idx >= NTOT*NTOT) return;
    int i = idx / NTOT, j = idx % NTOT;
    if (i > j) return;
    float s = (i == j) ? 0.001f : 0.f;
    for (int k = 0; k < NTOT; ++k) s += X[k*NTOT+i]*X[k*NTOT+j];
    const float* T  = ws + WS_T;
    const float* vr = ws + WS_VR;
    float s2 = 0.f;
    for (int k = 0; k < 64; ++k) s2 += T[i*64+k]*vr[j*64+k];
    s += s2;
    if (i < 192 && j < 192) {
        float s3 = 0.f;
        for (int k = 0; k < 32; ++k) {
            float qi = (i < 128) ? C2[k*128+i] : D21[k*64 + (i-128)];
            float qj = (j < 128) ? C2[k*128+j] : D21[k*64 + (j-128)];
            s3 += qi*qj;
        }
        s += 10.f*s3;
    }
    ws[WS_H + i*NTOT + j] = s;
    ws[WS_H + j*NTOT + i] = s;
}

// ---------------------------------------------------------------------------
// K3: extract
// ---------------------------------------------------------------------------
__global__ void k_extract(const float* __restrict__ Y1, const float* __restrict__ C2,
                          const float* __restrict__ D21, const float* __restrict__ D12,
                          const float* __restrict__ B2, float* __restrict__ ws)
{
    const float* H = ws + WS_H;
    unsigned short* bfb = (unsigned short*)(ws + WS_BFU);
    int tid = blockIdx.x*blockDim.x + threadIdx.x;
    int nth = gridDim.x*blockDim.x;
    for (int idx = tid; idx < 128*128; idx += nth) {
        int i = idx >> 7, j = idx & 127;
        ws[WS_E+idx] = 0.5f*(H[i*320+j] + H[(192+i)*320 + 192+j] + Y1[i*128+j] - Y1[j*128+i]);
    }
    for (int i = tid; i < 64; i += nth)
        ws[WS_ILAM+i] = 2.0f / H[(128+i)*320 + 128+i];
    for (int idx = tid; idx < 64*64; idx += nth) {
        int i = idx >> 6, j = idx & 63;
        ws[WS_D11+idx] = (j < i) ? -H[(128+i)*320 + 128+j] : 0.f;
    }
    for (int idx = tid; idx < 128*256; idx += nth) {
        int m = idx >> 8, k = idx & 255;
        ws[WS_WEXT+idx] = (k < 192) ? H[(192+m)*320 + k] : B2[m*64 + (k-192)];
    }
    for (int idx = tid; idx < 64*256; idx += nth) {
        int j = idx >> 8, k = idx & 255;
        float v;
        if (k < 128)      v = -H[(128+j)*320 + k];
        else if (k < 192) v = 0.f;
        else              v = D12[j*64 + (k-192)];
        unsigned short hi = f2bf(v);
        bfb[U_WATH+idx] = hi;
        bfb[U_WATL+idx] = f2bf(v - bf2f(hi));
    }
    const float* D22 = ws + WS_D22;
    for (int idx = tid; idx < 32*256; idx += nth) {
        int c = idx >> 8, k = idx & 255;
        float v;
        if (k < 128)      v = C2[c*128+k];
        else if (k < 192) v = D21[c*64 + (k-128)];
        else              v = D22[c*64 + (k-192)];
        bfb[U_WOT+idx] = f2bf(v);
    }
}

// ---------------------------------------------------------------------------
// Schur GEMM pieces. kS_PQ merges P and Q (both depend only on Ai).
// ---------------------------------------------------------------------------
__global__ __launch_bounds__(256) void kS_PQ(float* __restrict__ ws)
{
    int gid = blockIdx.x*256 + threadIdx.x;
    const float* E  = ws + WS_E;
    if (gid < 4096) {                 // P = Ai @ B
        int i = gid >> 6, j = gid & 63;
        const float* AI = ws + SC_AI + i*64;
        float s = 0.f;
        for (int k = 0; k < 64; ++k) s += AI[k] * E[k*128 + 64 + j];
        ws[SC_P + gid] = s;
    } else {                          // Q = C @ Ai
        int idx = gid - 4096;
        int i = idx >> 6, j = idx & 63;
        const float* C = E + (64+i)*128;
        const float* AI = ws + SC_AI;
        float s = 0.f;
        for (int k = 0; k < 64; ++k) s += C[k] * AI[k*64 + j];
        ws[SC_Q + idx] = s;
    }
}
__global__ __launch_bounds__(256) void kS_S(float* __restrict__ ws)
{
    int idx = blockIdx.x*256 + threadIdx.x;
    int i = idx >> 6, j = idx & 63;
    const float* E = ws + WS_E;
    const float* C = E + (64+i)*128;
    const float* P = ws + SC_P;
    float s = E[(64+i)*128 + 64 + j];
    for (int k = 0; k < 64; ++k) s -= C[k] * P[k*64 + j];
    ws[SC_S + idx] = s;
}
__global__ __launch_bounds__(256) void kS_R(float* __restrict__ ws)
{
    int idx = blockIdx.x*256 + threadIdx.x;
    int i = idx >> 6, j = idx & 63;
    const float* Si = ws + SC_S + i*64;
    const float* Q  = ws + SC_Q;
    float s = 0.f;
    for (int k = 0; k < 64; ++k) s += Si[k] * Q[k*64 + j];
    ws[SC_R + idx] = s;
    ws[WS_EINV + (64+i)*128 + j] = -s;
}
__global__ __launch_bounds__(256) void kS_TL(float* __restrict__ ws)
{
    int idx = blockIdx.x*256 + threadIdx.x;
    int i = idx >> 6, j = idx & 63;
    const float* P  = ws + SC_P + i*64;
    const float* R2 = ws + SC_R;
    const float* Si = ws + SC_S;
    float s1 = ws[SC_AI + idx];
    float s2 = 0.f;
    for (int k = 0; k < 64; ++k) {
        s1 += P[k] * R2[k*64 + j];
        s2 += P[k] * Si[k*64 + j];
    }
    ws[WS_EINV + i*128 + j]           = s1;
    ws[WS_EINV + i*128 + 64 + j]      = -s2;
    ws[WS_EINV + (64+i)*128 + 64 + j] = Si[i*64 + j];
}

// ---------------------------------------------------------------------------
// K5: Wsp
// ---------------------------------------------------------------------------
__global__ __launch_bounds__(256) void k_Wsp(float* __restrict__ ws)
{
    int i = blockIdx.x;
    int k = threadIdx.x;
    const float* Einv = ws + WS_EINV + i*128;
    const float* WexT = ws + WS_WEXT;
    unsigned short* bfb = (unsigned short*)(ws + WS_BFU);
    float s = 0.f;
    for (int m = 0; m < 128; ++m) s += Einv[m] * WexT[m*256 + k];
    unsigned short hi = f2bf(s);
    bfb[U_WSPH + i*256 + k] = hi;
    bfb[U_WSPL + i*256 + k] = f2bf(s - bf2f(hi));
}

// ---------------------------------------------------------------------------
// K6: batch kernel — R19/R21-EXACT ROWS=64 form (proven ~115us).
// ---------------------------------------------------------------------------
__global__ __launch_bounds__(256, 4) void k_batch(
    const float* __restrict__ inpt, const float* __restrict__ state,
    const float* __restrict__ ws, float* __restrict__ out)
{
    __shared__ unsigned short zsh[64*256];    // 32768 B
    __shared__ unsigned short D11t[64*64];    // 8192 B (transposed, bf16)
    const int t = threadIdx.x;
    const int row0 = blockIdx.x * 64;
    const unsigned short* bfb = (const unsigned short*)(ws + WS_BFU);

    for (int idx = t; idx < 64*16; idx += 256) {
        int r = idx >> 4, c = idx & 15;
        const float4* p = (const float4*)(state + (size_t)(row0+r)*128 + c*8);
        float4 f0 = p[0], f1 = p[1];
        short8 h;
        h[0]=(short)f2bf(f0.x); h[1]=(short)f2bf(f0.y); h[2]=(short)f2bf(f0.z); h[3]=(short)f2bf(f0.w);
        h[4]=(short)f2bf(f1.x); h[5]=(short)f2bf(f1.y); h[6]=(short)f2bf(f1.z); h[7]=(short)f2bf(f1.w);
        *(short8*)(&zsh[r*256 + ((c ^ (r&7)) << 3)]) = h;
    }
    for (int idx = t; idx < 64*8; idx += 256) {
        int r = idx >> 3, cl = idx & 7, c = 24 + cl;
        const float4* p = (const float4*)(inpt + (size_t)(row0+r)*64 + cl*8);
        float4 f0 = p[0], f1 = p[1];
        short8 h;
        h[0]=(short)f2bf(f0.x); h[1]=(short)f2bf(f0.y); h[2]=(short)f2bf(f0.z); h[3]=(short)f2bf(f0.w);
        h[4]=(short)f2bf(f1.x); h[5]=(short)f2bf(f1.y); h[6]=(short)f2bf(f1.z); h[7]=(short)f2bf(f1.w);
        *(short8*)(&zsh[r*256 + ((c ^ (r&7)) << 3)]) = h;
    }
    for (int idx = t; idx < 4096; idx += 256) {
        int j = idx >> 6, i = idx & 63;
        float v = (i == j) ? ws[WS_ILAM + j] : ws[WS_D11 + i*64 + j];
        D11t[idx] = f2bf(v);
    }
    __syncthreads();

    const int wv = t >> 6, lane = t & 63, lr = lane & 15, lk = lane >> 4;

    {
        const unsigned short* WATH = bfb + U_WATH;
        const unsigned short* WATL = bfb + U_WATL;
        f32x4 acc1[4] = {};
        const int ks1[6] = {0,1,2,3,6,7};
        #pragma unroll
        for (int s = 0; s < 6; ++s) {
            int ks = ks1[s];
            short8 bh = *(const short8*)(&WATH[(wv*16+lr)*256 + ks*32 + lk*8]);
            short8 bl = *(const short8*)(&WATL[(wv*16+lr)*256 + ks*32 + lk*8]);
            #pragma unroll
            for (int rt = 0; rt < 4; ++rt) {
                int row = rt*16 + lr, c = ks*4 + lk;
                short8 a = *(const short8*)(&zsh[row*256 + ((c ^ (row&7)) << 3)]);
                acc1[rt] = __builtin_amdgcn_mfma_f32_16x16x32_bf16(a, bh, acc1[rt], 0, 0, 0);
                acc1[rt] = __builtin_amdgcn_mfma_f32_16x16x32_bf16(a, bl, acc1[rt], 0, 0, 0);
            }
        }
        __syncthreads();
        const int ac = wv*16 + lr;
        const int cch = 16 + (ac >> 3), coff = ac & 7;
        #pragma unroll
        for (int rt = 0; rt < 4; ++rt)
            #pragma unroll
            for (int r = 0; r < 4; ++r) {
                int row = rt*16 + lk*4 + r;
                zsh[row*256 + ((cch ^ (row&7)) << 3) + coff] = f2bf(acc1[rt][r]);
            }
    }
    __syncthreads();

    {
        const int r  = wv*16 + (lane >> 2);
        const int qq = lane & 3;
        float acc[16];
        #pragma unroll
        for (int s = 0; s < 16; ++s) {
            int i = qq*16 + s;
            int cch = 16 + (i >> 3);
            acc[s] = bf2f(zsh[r*256 + ((cch ^ (r&7)) << 3) + (i & 7)]);
        }
        float wloc[16];
        #pragma unroll
        for (int j = 0; j < 64; ++j) {
            float diag = bf2f(D11t[j*64 + j]);
            float v = acc[j & 15];
            float x = v * diag;
            float e = __expf(2.f*x);
            float wc = 1.f - __fdividef(2.f, e + 1.f);
            int src = (lane & 0x3C) | (j >> 4);
            float wj = __shfl(wc, src, 64);
            if ((j >> 4) == qq) wloc[j & 15] = wj;
            #pragma unroll
            for (int s = 0; s < 16; ++s)
                acc[s] += wj * bf2f(D11t[j*64 + qq*16 + s]);
        }
        #pragma unroll
        for (int cc = 0; cc < 2; ++cc) {
            int ch = 16 + qq*2 + cc;
            short8 h;
            #pragma unroll
            for (int e2 = 0; e2 < 8; ++e2) h[e2] = (short)f2bf(wloc[cc*8 + e2]);
            *(short8*)(&zsh[r*256 + ((ch ^ (r&7)) << 3)]) = h;
        }
    }
    __syncthreads();

    {
        const unsigned short* WOT  = bfb + U_WOT;
        const unsigned short* WSPH = bfb + U_WSPH;
        const unsigned short* WSPL = bfb + U_WSPL;
        f32x4 acc[3][4] = {};
        const int nt = (wv < 2) ? 3 : 2;
        #pragma unroll
        for (int ks = 0; ks < 8; ++ks) {
            short8 afr[4];
            #pragma unroll
            for (int rt = 0; rt < 4; ++rt) {
                int row = rt*16 + lr, c = ks*4 + lk;
                afr[rt] = *(const short8*)(&zsh[row*256 + ((c ^ (row&7)) << 3)]);
            }
            #pragma unroll
            for (int tt = 0; tt < 3; ++tt) {
                if (tt < nt) {
                    int ct = wv + tt*4;
                    if (ct < 2) {
                        short8 b = *(const short8*)(&WOT[(ct*16+lr)*256 + ks*32 + lk*8]);
                        #pragma unroll
                        for (int rt = 0; rt < 4; ++rt)
                            acc[tt][rt] = __builtin_amdgcn_mfma_f32_16x16x32_bf16(afr[rt], b, acc[tt][rt], 0, 0, 0);
                    } else {
                        short8 bh = *(const short8*)(&WSPH[((ct-2)*16+lr)*256 + ks*32 + lk*8]);
                        short8 bl = *(const short8*)(&WSPL[((ct-2)*16+lr)*256 + ks*32 + lk*8]);
                        #pragma unroll
                        for (int rt = 0; rt < 4; ++rt) {
                            acc[tt][rt] = __builtin_amdgcn_mfma_f32_16x16x32_bf16(afr[rt], bh, acc[tt][rt], 0, 0, 0);
                            acc[tt][rt] = __builtin_amdgcn_mfma_f32_16x16x32_bf16(afr[rt], bl, acc[tt][rt], 0, 0, 0);
                        }
                    }
                }
            }
        }
        float* sp = out + (size_t)BATCH*32;
        #pragma unroll
        for (int tt = 0; tt < 3; ++tt) {
            if (tt < nt) {
                int ct = wv + tt*4;
                #pragma unroll
                for (int rt = 0; rt < 4; ++rt) {
                    int rowb = row0 + rt*16 + lk*4;
                    #pragma unroll
                    for (int r = 0; r < 4; ++r) {
                        float vv = acc[tt][rt][r];
                        if (ct < 2) out[(size_t)(rowb+r)*32  + ct*16 + lr]     = vv;
                        else        sp[(size_t)(rowb+r)*128 + (ct-2)*16 + lr] = vv;
                    }
                }
            }
        }
    }
}

extern "C" void kernel_launch(void* const* d_in, const int* in_sizes, int n_in,
                              void* d_out, int out_size, void* d_ws, size_t ws_size,
                              hipStream_t stream)
{
    const float* inpt  = (const float*)d_in[0];
    const float* state = (const float*)d_in[1];
    const float* X   = (const float*)d_in[2];
    const float* Y1  = (const float*)d_in[3];
    const float* X3  = (const float*)d_in[4];
    const float* Y3  = (const float*)d_in[5];
    const float* Z3  = (const float*)d_in[6];
    const float* B2  = (const float*)d_in[7];
    const float* C2  = (const float*)d_in[8];
    const float* D21 = (const float*)d_in[9];
    const float* D12 = (const float*)d_in[10];
    float* ws  = (float*)d_ws;
    float* out = (float*)d_out;

    kF_abc<<<1, 1024, 0, stream>>>(X3, Y3, Z3, ws);
    kS_gj64g<<<1, 256, 0, stream>>>(ws, WS_RC, 64, WS_RC, 64);   // Rinv
    k_vecrT<<<80, 256, 0, stream>>>(B2, C2, D21, D12, ws);
    k_H<<<(NTOT*NTOT + 255)/256, 256, 0, stream>>>(X, C2, D21, ws);
    k_extract<<<128, 256, 0, stream>>>(Y1, C2, D21, D12, B2, ws);
    kS_gj64g<<<1, 256, 0, stream>>>(ws, WS_E, 128, SC_AI, 64);   // Ai
    kS_PQ<<<32, 256, 0, stream>>>(ws);                           // P, Q
    kS_S<<<16, 256, 0, stream>>>(ws);                            // S
    kS_gj64g<<<1, 256, 0, stream>>>(ws, SC_S, 64, SC_S, 64);     // Si
    kS_R<<<16, 256, 0, stream>>>(ws);                            // R2; bl
    kS_TL<<<16, 256, 0, stream>>>(ws);                           // tl, tr, br
    k_Wsp<<<128, 256, 0, stream>>>(ws);
    k_batch<<<BATCH/64, 256, 0, stream>>>(inpt, state, ws, out);
}